// Round 1
// baseline (463.951 us; speedup 1.0000x reference)
//
#include <hip/hip_runtime.h>
#include <math.h>

#define BB      16
#define SECL    16
#define WORDL   256
#define SRCLEN  4096     // SECL*WORDL
#define DIM     1024
#define FSZ     2
#define GL      (FSZ*WORDL)   // 512 gathered positions per batch

// ---------------------------------------------------------------------------
// NOTE: d_ws is deliberately NOT touched. All scratch lives in dead regions
// of d_out (each scratch value is consumed strictly before the stage that
// overwrites its region with final output):
//   d_out layout (floats): context [0,16384) | attn_out [16384,81920) |
//                          cov_out [81920,147456)
//   dec_feature (16384 f) -> attn_out rows 0..3   (K1 writes, K2 reads,
//                                                  K3 zero-fill overwrites)
//   score_g     (8192 f)  -> cov_out rows 0..1    (K2 writes, K3 reads,
//                                                  K4 cov-write overwrites)
//   top-2 of focus: recomputed per wave (16-lane shuffle scan) — no storage.
// ---------------------------------------------------------------------------

// fast tanh: 1 - 2/(e^{2x}+1), with clamp so e^{2x} never overflows.
__device__ __forceinline__ float fast_tanh(float x) {
    x = fminf(fmaxf(x, -10.f), 10.f);
    float e = __expf(2.f * x);
    return 1.f - 2.f * __builtin_amdgcn_rcpf(e + 1.f);
}

// top-2 of focus[0..15] with jax.lax.top_k tie semantics (lowest index wins).
// All 64 lanes end with identical (i0,v0,i1,v1). Costs ~40 VALU ops.
__device__ __forceinline__ void wave_top2(const float* __restrict__ f, int lane,
                                          int& i0_, float& v0_, int& i1_, float& v1_)
{
    int idx = lane & 15;
    float x = f[idx];                 // replicated across the 4 groups of 16
    float m = x; int mi = idx;
    #pragma unroll
    for (int off = 8; off; off >>= 1) {
        float om = __shfl_xor(m, off);
        int   oi = __shfl_xor(mi, off);
        if (om > m || (om == m && oi < mi)) { m = om; mi = oi; }
    }
    i0_ = mi; v0_ = m;
    float x2 = (idx == mi) ? -INFINITY : x;
    float m2 = x2; int mi2 = idx;
    #pragma unroll
    for (int off = 8; off; off >>= 1) {
        float om = __shfl_xor(m2, off);
        int   oi = __shfl_xor(mi2, off);
        if (om > m2 || (om == m2 && oi < mi2)) { m2 = om; mi2 = oi; }
    }
    i1_ = mi2; v1_ = m2;
}

// ---------------------------------------------------------------------------
// K1: dec_feature[b][i] = b_dec[i] + dot(dec_hidden[b,:], W_dec[i,:])
//     blockIdx.x==16: zero context[b] (so K4 can atomicAdd, no memset).
// grid (17,16) x 256 threads. GEMM tile: 64 i-values per block, 4 threads/i.
// ---------------------------------------------------------------------------
__global__ __launch_bounds__(256) void k_decproj(
    const float* __restrict__ dec_hidden, const float* __restrict__ W_dec,
    const float* __restrict__ b_dec,
    float* __restrict__ dec_feature, float* __restrict__ context)
{
    if (blockIdx.x == 16) {
        int b = blockIdx.y;
        float4 z = {0.f, 0.f, 0.f, 0.f};
        ((float4*)(context + (size_t)b * DIM))[threadIdx.x] = z;
        return;
    }
    int b = blockIdx.y;
    int t = threadIdx.x;
    int i = blockIdx.x * 64 + (t >> 2);   // output column
    int c = t & 3;                        // k-chunk (256 floats each)
    const float4* Wr = (const float4*)(W_dec + (size_t)i * DIM + c * 256);
    const float4* Dr = (const float4*)(dec_hidden + (size_t)b * DIM + c * 256);
    float acc = 0.f;
    #pragma unroll 8
    for (int j = 0; j < 64; j++) {
        float4 w = Wr[j], d = Dr[j];
        acc += w.x*d.x + w.y*d.y + w.z*d.z + w.w*d.w;
    }
    acc += __shfl_down(acc, 2);
    acc += __shfl_down(acc, 1);
    if (c == 0) dec_feature[(size_t)b * DIM + i] = acc + b_dec[i];
}

// ---------------------------------------------------------------------------
// K2: gathered scores (one wave per gathered position, 8192 waves).
// grid 2048 x 256 threads (4 waves/block).
// ---------------------------------------------------------------------------
__global__ __launch_bounds__(256) void k_score(
    const float* __restrict__ enc_feature, const float* __restrict__ coverage,
    const float* __restrict__ dec_feature, const float* __restrict__ v,
    const float* __restrict__ w_cov, const float* __restrict__ focus,
    float* __restrict__ score_g)
{
    int w    = blockIdx.x * 4 + (threadIdx.x >> 6);   // wave id in [0, 8192)
    int lane = threadIdx.x & 63;
    int b  = w >> 9;           // 512 waves per batch
    int r  = w & 511;          // gathered index
    int k  = r >> 8;           // which of the 2 sections
    int wp = r & 255;          // word within section

    int i0, i1; float v0, v1;
    wave_top2(focus + b * SECL, lane, i0, v0, i1, v1);
    int sec = k ? i1 : i0;
    int s   = sec * WORDL + wp;

    float cv = coverage[(size_t)b * SRCLEN + s];
    const float4* ef = (const float4*)(enc_feature + ((size_t)b * SRCLEN + s) * DIM);
    const float4* df = (const float4*)(dec_feature + (size_t)b * DIM);
    const float4* vv = (const float4*)v;
    const float4* wc = (const float4*)w_cov;
    float acc = 0.f;
    #pragma unroll
    for (int q = 0; q < 4; q++) {
        int e4 = q * 64 + lane;                  // coalesced: 64 lanes x 16B
        float4 a = ef[e4], d = df[e4], wcv = wc[e4], vt = vv[e4];
        acc += fast_tanh(a.x + d.x + cv * wcv.x) * vt.x;
        acc += fast_tanh(a.y + d.y + cv * wcv.y) * vt.y;
        acc += fast_tanh(a.z + d.z + cv * wcv.z) * vt.z;
        acc += fast_tanh(a.w + d.w + cv * wcv.w) * vt.w;
    }
    #pragma unroll
    for (int off = 32; off; off >>= 1) acc += __shfl_down(acc, off);
    if (lane == 0) score_g[b * GL + r] = acc;
}

// ---------------------------------------------------------------------------
// K3: per-batch masked softmax over 512 gathered scores + focus scaling +
//     global renorm + zero-fill attn row + scatter into attn_out.
// Algebra: attn = f_k*e*mask / sum(f_k*e*mask)  (inner softmax norm cancels)
// grid 16 x 256 threads, 2 elements/thread.
// ---------------------------------------------------------------------------
__device__ __forceinline__ float block_reduce(float val, int is_max) {
    __shared__ float red[4];
    int lane = threadIdx.x & 63, wid = threadIdx.x >> 6;
    #pragma unroll
    for (int off = 32; off; off >>= 1) {
        float o = __shfl_down(val, off);
        val = is_max ? fmaxf(val, o) : val + o;
    }
    if (lane == 0) red[wid] = val;
    __syncthreads();
    if (threadIdx.x == 0) {
        float r = red[0];
        for (int i = 1; i < 4; i++) r = is_max ? fmaxf(r, red[i]) : r + red[i];
        red[0] = r;
    }
    __syncthreads();
    float result = red[0];
    __syncthreads();   // protect red[] before next call
    return result;
}

__global__ __launch_bounds__(256) void k_softmax_scatter(
    const float* __restrict__ enc_mask, const float* __restrict__ focus,
    const float* __restrict__ score_g, float* __restrict__ attn_out)
{
    int b = blockIdx.x;
    int t = threadIdx.x;
    int lane = t & 63;

    int i0, i1; float v0, v1;
    wave_top2(focus + b * SECL, lane, i0, v0, i1, v1);

    // zero-fill this batch's attn_dist row (4096 floats = 1024 float4).
    // (rows 0..3 held dec_feature — dead after K2, safe to wipe.)
    float4 z = {0.f, 0.f, 0.f, 0.f};
    float4* arow = (float4*)(attn_out + (size_t)b * SRCLEN);
    #pragma unroll
    for (int u = 0; u < 4; u++) arow[t + u * 256] = z;

    float sc[2], mk[2], fv[2];
    int ss[2];
    #pragma unroll
    for (int u = 0; u < 2; u++) {
        int r  = t + u * 256;
        int k  = r >> 8, wp = r & 255;
        int sec = k ? i1 : i0;
        int s   = sec * WORDL + wp;
        ss[u] = s;
        sc[u] = score_g[b * GL + r];
        mk[u] = enc_mask[(size_t)b * SRCLEN + s];
        fv[u] = k ? v1 : v0;
    }
    float m  = block_reduce(fmaxf(sc[0], sc[1]), 1);   // barriers inside also
    float e0 = __expf(sc[0] - m), e1 = __expf(sc[1] - m);
    float Tn = block_reduce(fv[0]*e0*mk[0] + fv[1]*e1*mk[1], 0);
    float inv = 1.0f / Tn;
    __syncthreads();   // ensure all zero-fills landed before scatter
    #pragma unroll
    for (int u = 0; u < 2; u++) {
        int r = t + u * 256;
        float a = fv[u] * (u ? e1 : e0) * mk[u] * inv;
        attn_out[(size_t)b * SRCLEN + ss[u]] = a;
    }
}

// ---------------------------------------------------------------------------
// K4: sp<16 : context[b][:] += attn * enc_output over 32 gathered rows
//     sp==16: cov_out row b = coverage row b + attn_out row b (full write —
//             this also overwrites the score_g scratch, which is dead here)
// grid (17,16) x 256 threads; atomicAdd partials (context zeroed by K1).
// ---------------------------------------------------------------------------
__global__ __launch_bounds__(256) void k_context_cov(
    const float* __restrict__ enc_output, const float* __restrict__ coverage,
    const float* __restrict__ focus, const float* __restrict__ attn_out,
    float* __restrict__ context, float* __restrict__ cov_out)
{
    int b  = blockIdx.y;
    int sp = blockIdx.x;        // 0..16
    int t  = threadIdx.x;

    if (sp == 16) {
        const float4* cv = (const float4*)(coverage + (size_t)b * SRCLEN);
        const float4* at = (const float4*)(attn_out + (size_t)b * SRCLEN);
        float4*       co = (float4*)(cov_out + (size_t)b * SRCLEN);
        #pragma unroll
        for (int u = 0; u < 4; u++) {
            int j = t + u * 256;
            float4 c = cv[j], a = at[j];
            c.x += a.x; c.y += a.y; c.z += a.z; c.w += a.w;
            co[j] = c;
        }
        return;
    }

    int lane = t & 63;
    int i0, i1; float v0, v1;
    wave_top2(focus + b * SECL, lane, i0, v0, i1, v1);

    float4 acc = {0.f, 0.f, 0.f, 0.f};
    #pragma unroll 4
    for (int j = 0; j < 32; j++) {
        int r  = sp * 32 + j;
        int k  = r >> 8, wp = r & 255;
        int s  = (k ? i1 : i0) * WORDL + wp;
        float a = attn_out[(size_t)b * SRCLEN + s];
        float4 e = ((const float4*)(enc_output + ((size_t)b * SRCLEN + s) * DIM))[t];
        acc.x += a * e.x; acc.y += a * e.y; acc.z += a * e.z; acc.w += a * e.w;
    }
    float* ctx = context + (size_t)b * DIM + t * 4;
    atomicAdd(ctx + 0, acc.x);
    atomicAdd(ctx + 1, acc.y);
    atomicAdd(ctx + 2, acc.z);
    atomicAdd(ctx + 3, acc.w);
}

// ---------------------------------------------------------------------------
extern "C" void kernel_launch(void* const* d_in, const int* in_sizes, int n_in,
                              void* d_out, int out_size, void* d_ws, size_t ws_size,
                              hipStream_t stream) {
    const float* dec_hidden  = (const float*)d_in[0];   // [16,1024]
    const float* enc_output  = (const float*)d_in[1];   // [16,4096,1024]
    const float* enc_feature = (const float*)d_in[2];   // [16,4096,1024]
    const float* enc_mask    = (const float*)d_in[3];   // [16,4096]
    // d_in[4] = sec_attn : unused by the reference
    const float* coverage    = (const float*)d_in[5];   // [16,4096]
    const float* focus       = (const float*)d_in[6];   // [16,16]
    const float* W_dec       = (const float*)d_in[7];   // [1024,1024]
    const float* b_dec       = (const float*)d_in[8];   // [1024]
    const float* v           = (const float*)d_in[9];   // [1024]
    const float* w_cov       = (const float*)d_in[10];  // [1024]

    float* out      = (float*)d_out;
    float* context  = out;                        // 16*1024  = 16384
    float* attn_out = out + 16384;                // 16*4096  = 65536
    float* cov_out  = out + 16384 + 65536;        // 16*4096  = 65536

    // scratch carved from dead d_out regions — d_ws is never touched
    float* dec_feature = attn_out;                // 16384 floats (attn rows 0..3)
    float* score_g     = cov_out;                 // 8192 floats  (cov rows 0..1)
    (void)d_ws; (void)ws_size;

    k_decproj<<<dim3(17, 16), 256, 0, stream>>>(
        dec_hidden, W_dec, b_dec, dec_feature, context);

    k_score<<<dim3(2048), 256, 0, stream>>>(
        enc_feature, coverage, dec_feature, v, w_cov, focus, score_g);

    k_softmax_scatter<<<dim3(16), 256, 0, stream>>>(
        enc_mask, focus, score_g, attn_out);

    k_context_cov<<<dim3(17, 16), 256, 0, stream>>>(
        enc_output, coverage, focus, attn_out, context, cov_out);
}